// Round 14
// baseline (86.926 us; speedup 1.0000x reference)
//
#include <hip/hip_runtime.h>

#define B_ 16
#define N_ 1024
#define F_ 256
#define H_ 4
#define QDIM 128

// 2*log2(e): folded into q,k so tanh arg feeds v_exp_f32 (exp2) directly
#define TANH_PRESCALE 2.8853900817779268f

typedef __attribute__((ext_vector_type(8))) short bf16x8;
typedef __attribute__((ext_vector_type(4))) float f32x4;
typedef __attribute__((ext_vector_type(2))) float f32x2;

__device__ __forceinline__ float leaky(float x) {
    return x >= 0.f ? x : 0.2f * x;
}

// f32 -> bf16 bits, round-to-nearest-even
__device__ __forceinline__ unsigned short bfbits(float f) {
    unsigned u = __float_as_uint(f);
    return (unsigned short)((u + 0x7fffu + ((u >> 16) & 1u)) >> 16);
}

__device__ __forceinline__ float bf2f(unsigned short u) {
    return __uint_as_float(((unsigned)u) << 16);
}

// DPP cross-lane add level (full-rate VALU, no LDS pipe). ctrl immediate.
template <int CTRL>
__device__ __forceinline__ float dpp_add(float x) {
    return x + __int_as_float(
        __builtin_amdgcn_update_dpp(0, __float_as_int(x), CTRL, 0xf, 0xf, true));
}

// wave64 sum reduce: 4 DPP levels + 2 shuffle levels.
__device__ __forceinline__ float wave_reduce_add(float x) {
    x = dpp_add<0xB1>(x);     // quad_perm xor1
    x = dpp_add<0x4E>(x);     // quad_perm xor2
    x = dpp_add<0x141>(x);    // row_half_mirror (== xor4 here)
    x = dpp_add<0x140>(x);    // row_mirror (== xor8 here)
    x += __shfl_xor(x, 16, 64);
    x += __shfl_xor(x, 32, 64);
    return x;
}

// ---------------------------------------------------------------------------
// K0: fused converts. blocks [0,2048): x f32->bf16 (8/thread);
//     blocks [2048,3072): Wq/Wk [h][f][q] -> [h][q][f] bf16.
// ---------------------------------------------------------------------------
__global__ __launch_bounds__(256) void convert_all(
    const float4* __restrict__ x4, ushort4* __restrict__ xh4,
    const float* __restrict__ Wq, const float* __restrict__ Wk,
    ushort* __restrict__ Wqt, ushort* __restrict__ Wkt)
{
    const int bx = blockIdx.x;
    if (bx < 2048) {
        const int t = bx * 256 + threadIdx.x;
        const float4 a = x4[2 * t], b = x4[2 * t + 1];
        ushort4 o0, o1;
        o0.x = bfbits(a.x); o0.y = bfbits(a.y); o0.z = bfbits(a.z); o0.w = bfbits(a.w);
        o1.x = bfbits(b.x); o1.y = bfbits(b.y); o1.z = bfbits(b.z); o1.w = bfbits(b.w);
        xh4[2 * t] = o0; xh4[2 * t + 1] = o1;
    } else {
        const int t2 = (bx - 2048) * 256 + threadIdx.x;   // 0..262143
        const int z = t2 >> 17, t = t2 & 131071;
        const int f = t & 255, q = (t >> 8) & 127, h = t >> 15;
        const float* W = z ? Wk : Wq;
        ushort* O = z ? Wkt : Wqt;
        O[t] = bfbits(W[(h * 256 + f) * 128 + q]);
    }
}

// ---------------------------------------------------------------------------
// K1: MFMA q/k projection. grid (256 m-tiles, 4 heads, 2 {q,k}), block 256.
// ---------------------------------------------------------------------------
__global__ __launch_bounds__(256) void qk_mfma(
    const ushort* __restrict__ xh,
    const ushort* __restrict__ Wqt, const ushort* __restrict__ Wkt,
    const float* __restrict__ aq, const float* __restrict__ bq,
    const float* __restrict__ ak, const float* __restrict__ bk,
    float* __restrict__ qbuf, float* __restrict__ kbuf)
{
    const int tid = threadIdx.x;
    const int mt  = blockIdx.x;
    const int h   = blockIdx.y;
    const bool isQ = (blockIdx.z == 0);
    const ushort* Wt = isQ ? Wqt : Wkt;
    const float*  av = isQ ? aq : ak;
    const float*  bv = isQ ? bq : bk;
    float* out = isQ ? qbuf : kbuf;

    __shared__ char  xs[64 * 512];       // 64 rows x 256 bf16 (swizzled)
    __shared__ float sp[4][64];

    {
        const int r = tid >> 2;
        const uint4* src = reinterpret_cast<const uint4*>(xh + (size_t)(mt * 64 + r) * 256);
        #pragma unroll
        for (int i = 0; i < 8; ++i) {
            const int c = (tid & 3) + 4 * i;
            const uint4 v = src[c];
            *reinterpret_cast<uint4*>(xs + r * 512 + ((c ^ (r & 7)) << 4)) = v;
        }
    }
    __syncthreads();

    const int l  = tid & 63, w = tid >> 6;
    const int g  = l >> 4, li = l & 15;

    bf16x8 Bf[8][2];
    #pragma unroll
    for (int nf = 0; nf < 2; ++nf) {
        const int c = w * 32 + nf * 16 + li;
        const ushort* bp = Wt + ((size_t)(h * 128 + c)) * 256 + 8 * g;
        #pragma unroll
        for (int s = 0; s < 8; ++s)
            Bf[s][nf] = *reinterpret_cast<const bf16x8*>(bp + s * 32);
    }

    f32x4 acc[4][2];
    #pragma unroll
    for (int m = 0; m < 4; ++m)
        #pragma unroll
        for (int nf = 0; nf < 2; ++nf)
            acc[m][nf] = (f32x4){0.f, 0.f, 0.f, 0.f};

    #pragma unroll
    for (int s = 0; s < 8; ++s) {
        #pragma unroll
        for (int m = 0; m < 4; ++m) {
            const int r = m * 16 + li;
            const int chunk = (4 * s + g) ^ (r & 7);
            const bf16x8 af = *reinterpret_cast<const bf16x8*>(xs + r * 512 + chunk * 16);
            acc[m][0] = __builtin_amdgcn_mfma_f32_16x16x32_bf16(af, Bf[s][0], acc[m][0], 0, 0, 0);
            acc[m][1] = __builtin_amdgcn_mfma_f32_16x16x32_bf16(af, Bf[s][1], acc[m][1], 0, 0, 0);
        }
    }

    float part[4][4];
    #pragma unroll
    for (int m = 0; m < 4; ++m)
        #pragma unroll
        for (int j = 0; j < 4; ++j) part[m][j] = 0.f;

    #pragma unroll
    for (int nf = 0; nf < 2; ++nf) {
        const float a_ = av[h * QDIM + w * 32 + nf * 16 + li];
        #pragma unroll
        for (int m = 0; m < 4; ++m)
            #pragma unroll
            for (int j = 0; j < 4; ++j)
                part[m][j] = fmaf(a_, leaky(acc[m][nf][j]), part[m][j]);
    }
    #pragma unroll
    for (int mask = 1; mask < 16; mask <<= 1)
        #pragma unroll
        for (int m = 0; m < 4; ++m)
            #pragma unroll
            for (int j = 0; j < 4; ++j)
                part[m][j] += __shfl_xor(part[m][j], mask, 64);

    if (li == 0) {
        #pragma unroll
        for (int m = 0; m < 4; ++m)
            #pragma unroll
            for (int j = 0; j < 4; ++j)
                sp[w][m * 16 + g * 4 + j] = part[m][j];
    }
    __syncthreads();

    if (tid < 64) {
        const float val = (sp[0][tid] + sp[1][tid] + sp[2][tid] + sp[3][tid] + bv[h]) * TANH_PRESCALE;
        const int R = mt * 64 + tid;
        out[((R >> 10) * H_ + h) * N_ + (R & 1023)] = val;
    }
}

// ---------------------------------------------------------------------------
// K2: scores + row-norm + masked column partial-sums. One pass over e.
// grid = (64 i-chunks of 16, B), block = 512.
// 8 waves = (row-quarter 0..3) x (head-group 0..1): each wave does 4 rows
// for TWO heads on ONE e load -> 2 independent chains/wave, half the VMEM.
// Quarter merge: 2-step LDS tree (32 KB, 2 barriers). Partials bf16.
// ---------------------------------------------------------------------------
__global__ __launch_bounds__(512) void attn_kernel(
    const float* __restrict__ e,
    const float* __restrict__ qbuf, const float* __restrict__ kbuf,
    const float* __restrict__ mask, const float* __restrict__ epsp,
    ushort* __restrict__ pbuf)
{
    const int tid  = threadIdx.x;
    const int wav  = tid >> 6;
    const int qtr  = wav & 3;                // row quarter
    const int hg   = wav >> 2;               // head group
    const int hA   = hg * 2, hB = hg * 2 + 1;
    const int lane = tid & 63;
    const int b    = blockIdx.y;
    const int ic   = blockIdx.x;             // 16-row chunk
    const int i0   = ic * 16 + qtr * 4;      // multiple of 4
    const float epsv = epsp[0];              // RAW: qk already carries C
    const int udiag = ic >> 4;               // (i>>8), uniform across chunk

    __shared__ f32x2 red[2][2][2][8][64];    // [slot][hg][hh][p][lane] 32 KB

    const f32x4* krA = reinterpret_cast<const f32x4*>(kbuf + (b * H_ + hA) * N_);
    const f32x4* krB = reinterpret_cast<const f32x4*>(kbuf + (b * H_ + hB) * N_);
    f32x2 kkA[8], kkB[8];
    #pragma unroll
    for (int u = 0; u < 4; ++u) {
        const f32x4 ka = krA[u * 64 + lane];
        const f32x4 kb = krB[u * 64 + lane];
        kkA[2 * u]     = __builtin_shufflevector(ka, ka, 0, 1);
        kkA[2 * u + 1] = __builtin_shufflevector(ka, ka, 2, 3);
        kkB[2 * u]     = __builtin_shufflevector(kb, kb, 0, 1);
        kkB[2 * u + 1] = __builtin_shufflevector(kb, kb, 2, 3);
    }

    f32x2 waccA[8], waccB[8];
    #pragma unroll
    for (int p = 0; p < 8; ++p) { waccA[p] = (f32x2){0.f, 0.f}; waccB[p] = (f32x2){0.f, 0.f}; }

    const float* qrowA = qbuf + (b * H_ + hA) * N_;
    const float* qrowB = qbuf + (b * H_ + hB) * N_;
    const float* mrow  = mask + b * N_;
    const f32x4* ebase = reinterpret_cast<const f32x4*>(e + ((size_t)b << 20)) + lane;

    const f32x2 one2 = {1.f, 1.f};
    const f32x2 m2   = {-2.f, -2.f};

    // diag lane predicate is uniform across this wave's 4 rows (i0 mult of 4)
    const bool isdl = (lane == ((i0 >> 2) & 63));
    const float dadd = isdl ? epsv : 0.f;

    #pragma unroll
    for (int ii = 0; ii < 4; ++ii) {
        const int i = i0 + ii;
        const float qiA = qrowA[i], qiB = qrowB[i];
        const f32x2 qiA2 = {qiA, qiA}, qiB2 = {qiB, qiB};

        const f32x4* er = ebase + ((size_t)i << 8);
        f32x4 ev[4];
        #pragma unroll
        for (int u = 0; u < 4; ++u) ev[u] = er[u * 64];

        f32x2 pvA[8], pvB[8];
        f32x2 sslA = {0.f, 0.f}, sslB = {0.f, 0.f};
        #pragma unroll
        for (int u = 0; u < 4; ++u) {
            #pragma unroll
            for (int s = 0; s < 2; ++s) {
                const int p = 2 * u + s;
                const f32x2 e2 = s ? __builtin_shufflevector(ev[u], ev[u], 2, 3)
                                   : __builtin_shufflevector(ev[u], ev[u], 0, 1);
                const f32x2 qkA = qiA2 + kkA[p];
                const f32x2 qkB = qiB2 + kkB[p];
                f32x2 argA = qkA * e2;
                f32x2 argB = qkB * e2;
                // diag col j==i: c = ii (<4) -> s-slot = ii>>1, elem = ii&1
                if (u == udiag && s == (ii >> 1)) {
                    const int cc = ii & 1;
                    argA[cc] = fmaf(qkA[cc], dadd, argA[cc]);
                    argB[cc] = fmaf(qkB[cc], dadd, argB[cc]);
                }
                f32x2 exA, exB;
                exA[0] = __builtin_amdgcn_exp2f(argA[0]);
                exB[0] = __builtin_amdgcn_exp2f(argB[0]);
                exA[1] = __builtin_amdgcn_exp2f(argA[1]);
                exB[1] = __builtin_amdgcn_exp2f(argB[1]);
                const f32x2 dA = exA + one2;
                const f32x2 dB = exB + one2;
                f32x2 rA, rB;
                rA[0] = __builtin_amdgcn_rcpf(dA[0]);
                rB[0] = __builtin_amdgcn_rcpf(dB[0]);
                rA[1] = __builtin_amdgcn_rcpf(dA[1]);
                rB[1] = __builtin_amdgcn_rcpf(dB[1]);
                const f32x2 pA = __builtin_elementwise_fma(rA, m2, one2);
                const f32x2 pB = __builtin_elementwise_fma(rB, m2, one2);
                pvA[p] = pA; pvB[p] = pB;
                sslA = __builtin_elementwise_fma(pA, pA, sslA);
                sslB = __builtin_elementwise_fma(pB, pB, sslB);
            }
        }
        // two independent reduce chains (interleavable)
        const float sA = wave_reduce_add(sslA[0] + sslA[1]);
        const float sB = wave_reduce_add(sslB[0] + sslB[1]);
        const float mi = mrow[i];
        const float scaleA = mi * __builtin_amdgcn_rcpf(sqrtf(sA) + 1e-7f);
        const float scaleB = mi * __builtin_amdgcn_rcpf(sqrtf(sB) + 1e-7f);
        const f32x2 scA = {scaleA, scaleA}, scB = {scaleB, scaleB};
        #pragma unroll
        for (int p = 0; p < 8; ++p) {
            waccA[p] = __builtin_elementwise_fma(scA, pvA[p], waccA[p]);
            waccB[p] = __builtin_elementwise_fma(scB, pvB[p], waccB[p]);
        }
    }

    // merge quarters: (1,3) write -> (0,2) add -> 2 writes -> 0 adds.
    if (qtr & 1) {
        #pragma unroll
        for (int p = 0; p < 8; ++p) {
            red[qtr >> 1][hg][0][p][lane] = waccA[p];
            red[qtr >> 1][hg][1][p][lane] = waccB[p];
        }
    }
    __syncthreads();
    if (!(qtr & 1)) {
        #pragma unroll
        for (int p = 0; p < 8; ++p) {
            waccA[p] += red[qtr >> 1][hg][0][p][lane];
            waccB[p] += red[qtr >> 1][hg][1][p][lane];
        }
        if (qtr == 2) {
            #pragma unroll
            for (int p = 0; p < 8; ++p) {
                red[1][hg][0][p][lane] = waccA[p];
                red[1][hg][1][p][lane] = waccB[p];
            }
        }
    }
    __syncthreads();
    if (qtr == 0) {
        #pragma unroll
        for (int p = 0; p < 8; ++p) {
            waccA[p] += red[1][hg][0][p][lane];
            waccB[p] += red[1][hg][1][p][lane];
        }
        #pragma unroll
        for (int hh = 0; hh < 2; ++hh) {
            ushort* pr = pbuf + ((size_t)((ic * 16 + b) * H_ + hA + hh) << 10);
            #pragma unroll
            for (int u = 0; u < 4; ++u) {
                const f32x2 a = hh ? waccB[2 * u]     : waccA[2 * u];
                const f32x2 c = hh ? waccB[2 * u + 1] : waccA[2 * u + 1];
                ushort4 o;
                o.x = bfbits(a[0]); o.y = bfbits(a[1]);
                o.z = bfbits(c[0]); o.w = bfbits(c[1]);
                *reinterpret_cast<ushort4*>(pr + u * 256 + lane * 4) = o;
            }
        }
    }
}

// ---------------------------------------------------------------------------
// K3a: partial-reduce (64 ic, bf16) + weighted row-sum of xh (bf16).
// grid 256 (b, jc of 64 j), block 256.
// ---------------------------------------------------------------------------
__global__ __launch_bounds__(256) void ypart_kernel(
    const ushort* __restrict__ xh, const ushort* __restrict__ pbuf,
    float* __restrict__ ypart)
{
    const int tid = threadIdx.x;
    const int bx  = blockIdx.x;
    const int b   = bx >> 4;
    const int jc  = bx & 15;
    const int j0  = jc * 64;

    __shared__ float ws_[H_][64];
    {
        const int hh = tid >> 6, j = tid & 63;   // exactly 256 = 4h x 64j
        const ushort* pp = pbuf + ((size_t)(b * H_ + hh) << 10) + j0 + j;
        float s0 = 0.f, s1 = 0.f, s2 = 0.f, s3 = 0.f;
        #pragma unroll 4
        for (int ic = 0; ic < 64; ic += 4) {
            s0 += bf2f(pp[(size_t)(ic + 0) * 65536]);
            s1 += bf2f(pp[(size_t)(ic + 1) * 65536]);
            s2 += bf2f(pp[(size_t)(ic + 2) * 65536]);
            s3 += bf2f(pp[(size_t)(ic + 3) * 65536]);
        }
        ws_[hh][j] = (s0 + s1) + (s2 + s3);
    }
    __syncthreads();

    float a0 = 0.f, a1 = 0.f, a2 = 0.f, a3 = 0.f;
    const ushort* xcol = xh + ((size_t)(b * N_ + j0)) * F_ + tid;
    #pragma unroll 4
    for (int j = 0; j < 64; ++j) {
        const float xv = bf2f(xcol[(size_t)j * F_]);
        a0 = fmaf(ws_[0][j], xv, a0);
        a1 = fmaf(ws_[1][j], xv, a1);
        a2 = fmaf(ws_[2][j], xv, a2);
        a3 = fmaf(ws_[3][j], xv, a3);
    }
    float* yp = ypart + (size_t)(b * 16 + jc) * (H_ * F_) + tid;
    yp[0 * F_] = a0; yp[1 * F_] = a1; yp[2 * F_] = a2; yp[3 * F_] = a3;
}

// ---------------------------------------------------------------------------
// K3b: out[b, h*128+v] = sum_f (sum_jc ypart[b,jc,h,f]) * Wv[h,f,v]
// ---------------------------------------------------------------------------
__global__ __launch_bounds__(256) void pool_kernel(
    const float* __restrict__ ypart, const float* __restrict__ Wv,
    float* __restrict__ out)
{
    const int tid = threadIdx.x;
    const int bh  = blockIdx.x;
    const int b   = bh >> 2;
    const int h   = bh & 3;
    __shared__ float ys[256];
    float s = 0.f;
    #pragma unroll
    for (int jc = 0; jc < 16; ++jc)
        s += ypart[(size_t)(b * 16 + jc) * (H_ * F_) + h * F_ + tid];
    ys[tid] = s;
    __syncthreads();
    if (tid < 128) {
        float acc = 0.f;
        const float* wv = Wv + h * (F_ * 128) + tid;
        #pragma unroll 4
        for (int f = 0; f < F_; ++f) acc = fmaf(ys[f], wv[f * 128], acc);
        out[bh * 128 + tid] = acc;
    }
}

extern "C" void kernel_launch(void* const* d_in, const int* in_sizes, int n_in,
                              void* d_out, int out_size, void* d_ws, size_t ws_size,
                              hipStream_t stream) {
    const float* e    = (const float*)d_in[0];
    const float* x    = (const float*)d_in[1];
    const float* mask = (const float*)d_in[2];
    const float* eps  = (const float*)d_in[3];
    const float* Wq   = (const float*)d_in[4];
    const float* Wk   = (const float*)d_in[5];
    const float* Wv   = (const float*)d_in[6];
    const float* aq   = (const float*)d_in[7];
    const float* bq   = (const float*)d_in[8];
    const float* ak   = (const float*)d_in[9];
    const float* bk   = (const float*)d_in[10];

    float*  qbuf  = (float*)d_ws;              // [B,H,N]         65536 f32
    float*  kbuf  = qbuf + 65536;              // [B,H,N]         65536 f32
    float*  ypartb= kbuf + 65536;              // [B,16,H,F]     262144 f32
    ushort* pbuf  = (ushort*)(ypartb + 262144);// [64,B,H,N] bf16 4194304
    ushort* xh    = pbuf + 4194304;            // [B*N,F] bf16   4194304
    ushort* Wqt   = xh + 4194304;              // [H,Q,F] bf16    131072
    ushort* Wkt   = Wqt + 131072;              // [H,Q,F] bf16    131072
    float*  outf  = (float*)d_out;

    convert_all<<<3072, 256, 0, stream>>>((const float4*)x, (ushort4*)xh, Wq, Wk, Wqt, Wkt);
    qk_mfma<<<dim3(256, 4, 2), 256, 0, stream>>>(xh, Wqt, Wkt, aq, bq, ak, bk, qbuf, kbuf);
    attn_kernel<<<dim3(64, 16), 512, 0, stream>>>(e, qbuf, kbuf, mask, eps, pbuf);
    ypart_kernel<<<256, 256, 0, stream>>>(xh, pbuf, ypartb);
    pool_kernel<<<64, 256, 0, stream>>>(ypartb, Wv, outf);
}

// Round 15
// 79.269 us; speedup vs baseline: 1.0966x; 1.0966x over previous
//
#include <hip/hip_runtime.h>

#define B_ 16
#define N_ 1024
#define F_ 256
#define H_ 4
#define QDIM 128

// 2*log2(e): folded into q,k so tanh arg feeds v_exp_f32 (exp2) directly
#define TANH_PRESCALE 2.8853900817779268f

typedef __attribute__((ext_vector_type(8))) short bf16x8;
typedef __attribute__((ext_vector_type(4))) float f32x4;
typedef __attribute__((ext_vector_type(2))) float f32x2;

__device__ __forceinline__ float leaky(float x) {
    return x >= 0.f ? x : 0.2f * x;
}

// f32 -> bf16 bits, round-to-nearest-even
__device__ __forceinline__ unsigned short bfbits(float f) {
    unsigned u = __float_as_uint(f);
    return (unsigned short)((u + 0x7fffu + ((u >> 16) & 1u)) >> 16);
}

__device__ __forceinline__ float bf2f(unsigned short u) {
    return __uint_as_float(((unsigned)u) << 16);
}

// DPP cross-lane add level (full-rate VALU, no LDS pipe). ctrl immediate.
template <int CTRL>
__device__ __forceinline__ float dpp_add(float x) {
    return x + __int_as_float(
        __builtin_amdgcn_update_dpp(0, __float_as_int(x), CTRL, 0xf, 0xf, true));
}

// wave64 sum reduce: 4 DPP levels + 2 shuffle levels.
__device__ __forceinline__ float wave_reduce_add(float x) {
    x = dpp_add<0xB1>(x);     // quad_perm xor1
    x = dpp_add<0x4E>(x);     // quad_perm xor2
    x = dpp_add<0x141>(x);    // row_half_mirror (== xor4 here)
    x = dpp_add<0x140>(x);    // row_mirror (== xor8 here)
    x += __shfl_xor(x, 16, 64);
    x += __shfl_xor(x, 32, 64);
    return x;
}

// ---------------------------------------------------------------------------
// K0: Wq/Wk [h][f][q] f32 -> Wqt/Wkt [h][q][f] bf16 (transposed). 1 MB, tiny.
// ---------------------------------------------------------------------------
__global__ __launch_bounds__(256) void convert_w(
    const float* __restrict__ Wq, const float* __restrict__ Wk,
    ushort* __restrict__ Wqt, ushort* __restrict__ Wkt)
{
    const int t = blockIdx.x * 256 + threadIdx.x;     // 0..131071
    const int f = t & 255, q = (t >> 8) & 127, h = t >> 15;
    const float* W = blockIdx.y ? Wk : Wq;
    ushort* O = blockIdx.y ? Wkt : Wqt;
    O[t] = bfbits(W[(h * 256 + f) * 128 + q]);
}

// ---------------------------------------------------------------------------
// K1: MFMA q/k projection. grid (256 m-tiles, 4 heads, 2 {q,k}), block 256.
// Stages A directly from f32 x with in-register RNE cvt (no xh pass).
// ---------------------------------------------------------------------------
__global__ __launch_bounds__(256) void qk_mfma(
    const float* __restrict__ x,
    const ushort* __restrict__ Wqt, const ushort* __restrict__ Wkt,
    const float* __restrict__ aq, const float* __restrict__ bq,
    const float* __restrict__ ak, const float* __restrict__ bk,
    float* __restrict__ qbuf, float* __restrict__ kbuf)
{
    const int tid = threadIdx.x;
    const int mt  = blockIdx.x;
    const int h   = blockIdx.y;
    const bool isQ = (blockIdx.z == 0);
    const ushort* Wt = isQ ? Wqt : Wkt;
    const float*  av = isQ ? aq : ak;
    const float*  bv = isQ ? bq : bk;
    float* out = isQ ? qbuf : kbuf;

    __shared__ char  xs[64 * 512];       // 64 rows x 256 bf16 (swizzled)
    __shared__ float sp[4][64];

    // stage A from f32: thread t -> row r = t>>2, bf16 16B chunks c=(t&3)+4i
    {
        const int r = tid >> 2;
        const float* src = x + (size_t)(mt * 64 + r) * 256;
        #pragma unroll
        for (int i = 0; i < 8; ++i) {
            const int c = (tid & 3) + 4 * i;
            const float4 v0 = *reinterpret_cast<const float4*>(src + c * 8);
            const float4 v1 = *reinterpret_cast<const float4*>(src + c * 8 + 4);
            ushort4 o0, o1;
            o0.x = bfbits(v0.x); o0.y = bfbits(v0.y); o0.z = bfbits(v0.z); o0.w = bfbits(v0.w);
            o1.x = bfbits(v1.x); o1.y = bfbits(v1.y); o1.z = bfbits(v1.z); o1.w = bfbits(v1.w);
            char* dst = xs + r * 512 + ((c ^ (r & 7)) << 4);
            *reinterpret_cast<ushort4*>(dst) = o0;
            *reinterpret_cast<ushort4*>(dst + 8) = o1;
        }
    }
    __syncthreads();

    const int l  = tid & 63, w = tid >> 6;
    const int g  = l >> 4, li = l & 15;

    bf16x8 Bf[8][2];
    #pragma unroll
    for (int nf = 0; nf < 2; ++nf) {
        const int c = w * 32 + nf * 16 + li;
        const ushort* bp = Wt + ((size_t)(h * 128 + c)) * 256 + 8 * g;
        #pragma unroll
        for (int s = 0; s < 8; ++s)
            Bf[s][nf] = *reinterpret_cast<const bf16x8*>(bp + s * 32);
    }

    f32x4 acc[4][2];
    #pragma unroll
    for (int m = 0; m < 4; ++m)
        #pragma unroll
        for (int nf = 0; nf < 2; ++nf)
            acc[m][nf] = (f32x4){0.f, 0.f, 0.f, 0.f};

    #pragma unroll
    for (int s = 0; s < 8; ++s) {
        #pragma unroll
        for (int m = 0; m < 4; ++m) {
            const int r = m * 16 + li;
            const int chunk = (4 * s + g) ^ (r & 7);
            const bf16x8 af = *reinterpret_cast<const bf16x8*>(xs + r * 512 + chunk * 16);
            acc[m][0] = __builtin_amdgcn_mfma_f32_16x16x32_bf16(af, Bf[s][0], acc[m][0], 0, 0, 0);
            acc[m][1] = __builtin_amdgcn_mfma_f32_16x16x32_bf16(af, Bf[s][1], acc[m][1], 0, 0, 0);
        }
    }

    float part[4][4];
    #pragma unroll
    for (int m = 0; m < 4; ++m)
        #pragma unroll
        for (int j = 0; j < 4; ++j) part[m][j] = 0.f;

    #pragma unroll
    for (int nf = 0; nf < 2; ++nf) {
        const float a_ = av[h * QDIM + w * 32 + nf * 16 + li];
        #pragma unroll
        for (int m = 0; m < 4; ++m)
            #pragma unroll
            for (int j = 0; j < 4; ++j)
                part[m][j] = fmaf(a_, leaky(acc[m][nf][j]), part[m][j]);
    }
    #pragma unroll
    for (int mask = 1; mask < 16; mask <<= 1)
        #pragma unroll
        for (int m = 0; m < 4; ++m)
            #pragma unroll
            for (int j = 0; j < 4; ++j)
                part[m][j] += __shfl_xor(part[m][j], mask, 64);

    if (li == 0) {
        #pragma unroll
        for (int m = 0; m < 4; ++m)
            #pragma unroll
            for (int j = 0; j < 4; ++j)
                sp[w][m * 16 + g * 4 + j] = part[m][j];
    }
    __syncthreads();

    if (tid < 64) {
        const float val = (sp[0][tid] + sp[1][tid] + sp[2][tid] + sp[3][tid] + bv[h]) * TANH_PRESCALE;
        const int R = mt * 64 + tid;
        out[((R >> 10) * H_ + h) * N_ + (R & 1023)] = val;
    }
}

// ---------------------------------------------------------------------------
// K2: scores + row-norm + masked column partial-sums. One pass over e.
// grid = (64 i-chunks of 16, B), block = 512 (8 waves = half x head).
// Lane owns j = u*256 + lane*4 + c. Row PAIRS (2x ILP, r11 structure).
// Partials stored bf16. No atomics. [best measured config: 80.2 us total]
// ---------------------------------------------------------------------------
__global__ __launch_bounds__(512) void attn_kernel(
    const float* __restrict__ e,
    const float* __restrict__ qbuf, const float* __restrict__ kbuf,
    const float* __restrict__ mask, const float* __restrict__ epsp,
    ushort* __restrict__ pbuf)
{
    const int tid  = threadIdx.x;
    const int wav  = tid >> 6;
    const int h    = wav & 3;
    const int half = wav >> 2;
    const int lane = tid & 63;
    const int b    = blockIdx.y;
    const int ic   = blockIdx.x;
    const int i0   = ic * 16 + half * 8;     // even
    const float epsv = epsp[0];              // RAW: qk already carries C
    const int udiag = ic >> 4;               // (i>>8), uniform across chunk

    __shared__ f32x2 red2[4][8][64];         // 16 KB

    const f32x4* kr4 = reinterpret_cast<const f32x4*>(kbuf + (b * H_ + h) * N_);
    f32x2 kk2[8];
    #pragma unroll
    for (int u = 0; u < 4; ++u) {
        const f32x4 kv = kr4[u * 64 + lane];
        kk2[2 * u]     = __builtin_shufflevector(kv, kv, 0, 1);
        kk2[2 * u + 1] = __builtin_shufflevector(kv, kv, 2, 3);
    }

    f32x2 wacc2[8];
    #pragma unroll
    for (int p = 0; p < 8; ++p) wacc2[p] = (f32x2){0.f, 0.f};

    const float* qrow  = qbuf + (b * H_ + h) * N_;
    const float* mrow  = mask + b * N_;
    const f32x4* ebase = reinterpret_cast<const f32x4*>(e + ((size_t)b << 20)) + lane;

    const f32x2 one2 = {1.f, 1.f};
    const f32x2 m2   = {-2.f, -2.f};

    #pragma unroll
    for (int ii = 0; ii < 8; ii += 2) {
        const int iA = i0 + ii, iB = iA + 1;
        const float qiA = qrow[iA], qiB = qrow[iB];
        const f32x2 qiA2 = {qiA, qiA}, qiB2 = {qiB, qiB};
        // even/odd pair: same lane predicate, slots cc=0 (A) and cc=1 (B)
        const bool isdl = (lane == ((iA >> 2) & 63));
        const float dadd = isdl ? epsv : 0.f;

        // issue both rows' loads up front (8 independent dwordx4)
        const f32x4* erA = ebase + ((size_t)iA << 8);
        const f32x4* erB = ebase + ((size_t)iB << 8);
        f32x4 evA[4], evB[4];
        #pragma unroll
        for (int u = 0; u < 4; ++u) { evA[u] = erA[u * 64]; evB[u] = erB[u * 64]; }

        f32x2 pvA[8], pvB[8];
        f32x2 sslA = {0.f, 0.f}, sslB = {0.f, 0.f};
        #pragma unroll
        for (int u = 0; u < 4; ++u) {
            #pragma unroll
            for (int s = 0; s < 2; ++s) {
                const int p = 2 * u + s;
                const f32x2 eA2 = s ? __builtin_shufflevector(evA[u], evA[u], 2, 3)
                                    : __builtin_shufflevector(evA[u], evA[u], 0, 1);
                const f32x2 eB2 = s ? __builtin_shufflevector(evB[u], evB[u], 2, 3)
                                    : __builtin_shufflevector(evB[u], evB[u], 0, 1);
                const f32x2 qkA = qiA2 + kk2[p];
                const f32x2 qkB = qiB2 + kk2[p];
                f32x2 argA = qkA * eA2;
                f32x2 argB = qkB * eB2;
                if (u == udiag && s == ((ii & 3) >> 1)) {  // compile-time
                    argA[0] = fmaf(qkA[0], dadd, argA[0]);   // row A: cc=0
                    argB[1] = fmaf(qkB[1], dadd, argB[1]);   // row B: cc=1
                }
                f32x2 exA, exB;
                exA[0] = __builtin_amdgcn_exp2f(argA[0]);
                exB[0] = __builtin_amdgcn_exp2f(argB[0]);
                exA[1] = __builtin_amdgcn_exp2f(argA[1]);
                exB[1] = __builtin_amdgcn_exp2f(argB[1]);
                const f32x2 dA = exA + one2;
                const f32x2 dB = exB + one2;
                f32x2 rA, rB;
                rA[0] = __builtin_amdgcn_rcpf(dA[0]);
                rB[0] = __builtin_amdgcn_rcpf(dB[0]);
                rA[1] = __builtin_amdgcn_rcpf(dA[1]);
                rB[1] = __builtin_amdgcn_rcpf(dB[1]);
                const f32x2 pA = __builtin_elementwise_fma(rA, m2, one2);
                const f32x2 pB = __builtin_elementwise_fma(rB, m2, one2);
                pvA[p] = pA; pvB[p] = pB;
                sslA = __builtin_elementwise_fma(pA, pA, sslA);
                sslB = __builtin_elementwise_fma(pB, pB, sslB);
            }
        }
        // two independent reduce chains (interleavable)
        const float sA = wave_reduce_add(sslA[0] + sslA[1]);
        const float sB = wave_reduce_add(sslB[0] + sslB[1]);
        const float scaleA = mrow[iA] * __builtin_amdgcn_rcpf(sqrtf(sA) + 1e-7f);
        const float scaleB = mrow[iB] * __builtin_amdgcn_rcpf(sqrtf(sB) + 1e-7f);
        const f32x2 scA = {scaleA, scaleA}, scB = {scaleB, scaleB};
        #pragma unroll
        for (int p = 0; p < 8; ++p) {
            wacc2[p] = __builtin_elementwise_fma(scA, pvA[p], wacc2[p]);
            wacc2[p] = __builtin_elementwise_fma(scB, pvB[p], wacc2[p]);
        }
    }

    if (half == 1) {
        #pragma unroll
        for (int p = 0; p < 8; ++p) red2[h][p][lane] = wacc2[p];
    }
    __syncthreads();
    if (half == 0) {
        ushort* pr = pbuf + ((size_t)((ic * 16 + b) * H_ + h) << 10);
        #pragma unroll
        for (int u = 0; u < 4; ++u) {
            const f32x2 a = wacc2[2 * u]     + red2[h][2 * u][lane];
            const f32x2 c = wacc2[2 * u + 1] + red2[h][2 * u + 1][lane];
            ushort4 o;
            o.x = bfbits(a[0]); o.y = bfbits(a[1]);
            o.z = bfbits(c[0]); o.w = bfbits(c[1]);
            *reinterpret_cast<ushort4*>(pr + u * 256 + lane * 4) = o;
        }
    }
}

// ---------------------------------------------------------------------------
// K3a: partial-reduce (64 ic, bf16) + weighted row-sum of x (f32).
// grid 256 (b, jc of 64 j), block 256.
// ---------------------------------------------------------------------------
__global__ __launch_bounds__(256) void ypart_kernel(
    const float* __restrict__ x, const ushort* __restrict__ pbuf,
    float* __restrict__ ypart)
{
    const int tid = threadIdx.x;
    const int bx  = blockIdx.x;
    const int b   = bx >> 4;
    const int jc  = bx & 15;
    const int j0  = jc * 64;

    __shared__ float ws_[H_][64];
    {
        const int hh = tid >> 6, j = tid & 63;   // exactly 256 = 4h x 64j
        const ushort* pp = pbuf + ((size_t)(b * H_ + hh) << 10) + j0 + j;
        float s0 = 0.f, s1 = 0.f, s2 = 0.f, s3 = 0.f;
        #pragma unroll 4
        for (int ic = 0; ic < 64; ic += 4) {
            s0 += bf2f(pp[(size_t)(ic + 0) * 65536]);
            s1 += bf2f(pp[(size_t)(ic + 1) * 65536]);
            s2 += bf2f(pp[(size_t)(ic + 2) * 65536]);
            s3 += bf2f(pp[(size_t)(ic + 3) * 65536]);
        }
        ws_[hh][j] = (s0 + s1) + (s2 + s3);
    }
    __syncthreads();

    float a0 = 0.f, a1 = 0.f, a2 = 0.f, a3 = 0.f;
    const float* xcol = x + ((size_t)(b * N_ + j0)) * F_ + tid;
    #pragma unroll 4
    for (int j = 0; j < 64; ++j) {
        const float xv = xcol[(size_t)j * F_];
        a0 = fmaf(ws_[0][j], xv, a0);
        a1 = fmaf(ws_[1][j], xv, a1);
        a2 = fmaf(ws_[2][j], xv, a2);
        a3 = fmaf(ws_[3][j], xv, a3);
    }
    float* yp = ypart + (size_t)(b * 16 + jc) * (H_ * F_) + tid;
    yp[0 * F_] = a0; yp[1 * F_] = a1; yp[2 * F_] = a2; yp[3 * F_] = a3;
}

// ---------------------------------------------------------------------------
// K3b: out[b, h*128+v] = sum_f (sum_jc ypart[b,jc,h,f]) * Wv[h,f,v]
// ---------------------------------------------------------------------------
__global__ __launch_bounds__(256) void pool_kernel(
    const float* __restrict__ ypart, const float* __restrict__ Wv,
    float* __restrict__ out)
{
    const int tid = threadIdx.x;
    const int bh  = blockIdx.x;
    const int b   = bh >> 2;
    const int h   = bh & 3;
    __shared__ float ys[256];
    float s = 0.f;
    #pragma unroll
    for (int jc = 0; jc < 16; ++jc)
        s += ypart[(size_t)(b * 16 + jc) * (H_ * F_) + h * F_ + tid];
    ys[tid] = s;
    __syncthreads();
    if (tid < 128) {
        float acc = 0.f;
        const float* wv = Wv + h * (F_ * 128) + tid;
        #pragma unroll 4
        for (int f = 0; f < F_; ++f) acc = fmaf(ys[f], wv[f * 128], acc);
        out[bh * 128 + tid] = acc;
    }
}

extern "C" void kernel_launch(void* const* d_in, const int* in_sizes, int n_in,
                              void* d_out, int out_size, void* d_ws, size_t ws_size,
                              hipStream_t stream) {
    const float* e    = (const float*)d_in[0];
    const float* x    = (const float*)d_in[1];
    const float* mask = (const float*)d_in[2];
    const float* eps  = (const float*)d_in[3];
    const float* Wq   = (const float*)d_in[4];
    const float* Wk   = (const float*)d_in[5];
    const float* Wv   = (const float*)d_in[6];
    const float* aq   = (const float*)d_in[7];
    const float* bq   = (const float*)d_in[8];
    const float* ak   = (const float*)d_in[9];
    const float* bk   = (const float*)d_in[10];

    float*  qbuf  = (float*)d_ws;              // [B,H,N]         65536 f32
    float*  kbuf  = qbuf + 65536;              // [B,H,N]         65536 f32
    float*  ypartb= kbuf + 65536;              // [B,16,H,F]     262144 f32
    ushort* pbuf  = (ushort*)(ypartb + 262144);// [64,B,H,N] bf16 4194304
    ushort* Wqt   = pbuf + 4194304;            // [H,Q,F] bf16    131072
    ushort* Wkt   = Wqt + 131072;              // [H,Q,F] bf16    131072
    float*  outf  = (float*)d_out;

    convert_w<<<dim3(512, 2), 256, 0, stream>>>(Wq, Wk, Wqt, Wkt);
    qk_mfma<<<dim3(256, 4, 2), 256, 0, stream>>>(x, Wqt, Wkt, aq, bq, ak, bk, qbuf, kbuf);
    attn_kernel<<<dim3(64, 16), 512, 0, stream>>>(e, qbuf, kbuf, mask, eps, pbuf);
    ypart_kernel<<<256, 256, 0, stream>>>(x, pbuf, ypartb);
    pool_kernel<<<64, 256, 0, stream>>>(ypartb, Wv, outf);
}

// Round 16
// 73.632 us; speedup vs baseline: 1.1805x; 1.0766x over previous
//
#include <hip/hip_runtime.h>

#define B_ 16
#define N_ 1024
#define F_ 256
#define H_ 4
#define QDIM 128

// 2*log2(e): folded into q,k so tanh arg feeds v_exp_f32 (exp2) directly
#define TANH_PRESCALE 2.8853900817779268f

typedef __attribute__((ext_vector_type(8))) short bf16x8;
typedef __attribute__((ext_vector_type(4))) float f32x4;
typedef __attribute__((ext_vector_type(2))) float f32x2;

__device__ __forceinline__ float leaky(float x) {
    return x >= 0.f ? x : 0.2f * x;
}

// f32 -> bf16 bits, round-to-nearest-even
__device__ __forceinline__ unsigned short bfbits(float f) {
    unsigned u = __float_as_uint(f);
    return (unsigned short)((u + 0x7fffu + ((u >> 16) & 1u)) >> 16);
}

__device__ __forceinline__ float bf2f(unsigned short u) {
    return __uint_as_float(((unsigned)u) << 16);
}

// DPP cross-lane add level (full-rate VALU, no LDS pipe). ctrl immediate.
template <int CTRL>
__device__ __forceinline__ float dpp_add(float x) {
    return x + __int_as_float(
        __builtin_amdgcn_update_dpp(0, __float_as_int(x), CTRL, 0xf, 0xf, true));
}

// wave64 sum reduce: 4 DPP levels + 2 shuffle levels.
__device__ __forceinline__ float wave_reduce_add(float x) {
    x = dpp_add<0xB1>(x);     // quad_perm xor1
    x = dpp_add<0x4E>(x);     // quad_perm xor2
    x = dpp_add<0x141>(x);    // row_half_mirror (== xor4 here)
    x = dpp_add<0x140>(x);    // row_mirror (== xor8 here)
    x += __shfl_xor(x, 16, 64);
    x += __shfl_xor(x, 32, 64);
    return x;
}

// ---------------------------------------------------------------------------
// K0: Wq/Wk [h][f][q] f32 -> fragment-ordered bf16: W2[h][s][g][c][j],
// f = s*32 + 8g + j, q = c. Makes qk_mfma's B-frag loads COALESCED
// (16 lanes x 16B contiguous per group). 1 MB, tiny.
// ---------------------------------------------------------------------------
__global__ __launch_bounds__(256) void convert_w(
    const float* __restrict__ Wq, const float* __restrict__ Wk,
    ushort* __restrict__ Wqt, ushort* __restrict__ Wkt)
{
    const int t = blockIdx.x * 256 + threadIdx.x;     // 0..131071
    const int j = t & 7;
    const int c = (t >> 3) & 127;
    const int g = (t >> 10) & 3;
    const int s = (t >> 12) & 7;
    const int h = t >> 15;
    const int f = s * 32 + 8 * g + j;
    const float* W = blockIdx.y ? Wk : Wq;
    ushort* O = blockIdx.y ? Wkt : Wqt;
    O[t] = bfbits(W[(h * 256 + f) * 128 + c]);
}

// ---------------------------------------------------------------------------
// K1: MFMA q/k projection. grid (256 m-tiles, 4 heads, 2 {q,k}), block 256.
// Stages A directly from f32 x with in-register RNE cvt; B-frags from the
// fragment-ordered W2 layout (coalesced).
// ---------------------------------------------------------------------------
__global__ __launch_bounds__(256) void qk_mfma(
    const float* __restrict__ x,
    const ushort* __restrict__ Wqt, const ushort* __restrict__ Wkt,
    const float* __restrict__ aq, const float* __restrict__ bq,
    const float* __restrict__ ak, const float* __restrict__ bk,
    float* __restrict__ qbuf, float* __restrict__ kbuf)
{
    const int tid = threadIdx.x;
    const int mt  = blockIdx.x;
    const int h   = blockIdx.y;
    const bool isQ = (blockIdx.z == 0);
    const ushort* Wt = isQ ? Wqt : Wkt;
    const float*  av = isQ ? aq : ak;
    const float*  bv = isQ ? bq : bk;
    float* out = isQ ? qbuf : kbuf;

    __shared__ char  xs[64 * 512];       // 64 rows x 256 bf16 (swizzled)
    __shared__ float sp[4][64];

    // stage A from f32: thread t -> row r = t>>2, bf16 16B chunks c=(t&3)+4i
    {
        const int r = tid >> 2;
        const float* src = x + (size_t)(mt * 64 + r) * 256;
        #pragma unroll
        for (int i = 0; i < 8; ++i) {
            const int c = (tid & 3) + 4 * i;
            const float4 v0 = *reinterpret_cast<const float4*>(src + c * 8);
            const float4 v1 = *reinterpret_cast<const float4*>(src + c * 8 + 4);
            ushort4 o0, o1;
            o0.x = bfbits(v0.x); o0.y = bfbits(v0.y); o0.z = bfbits(v0.z); o0.w = bfbits(v0.w);
            o1.x = bfbits(v1.x); o1.y = bfbits(v1.y); o1.z = bfbits(v1.z); o1.w = bfbits(v1.w);
            char* dst = xs + r * 512 + ((c ^ (r & 7)) << 4);
            *reinterpret_cast<ushort4*>(dst) = o0;
            *reinterpret_cast<ushort4*>(dst + 8) = o1;
        }
    }
    __syncthreads();

    const int l  = tid & 63, w = tid >> 6;
    const int g  = l >> 4, li = l & 15;

    // B frags: Bf[s][nf][j] = W[h][s*32+8g+j][c], c = w*32+nf*16+li.
    // W2 addr = (((h*8+s)*4+g)*128 + c)*8 -> lanes li consecutive 16B chunks.
    bf16x8 Bf[8][2];
    #pragma unroll
    for (int nf = 0; nf < 2; ++nf) {
        const int c = w * 32 + nf * 16 + li;
        #pragma unroll
        for (int s = 0; s < 8; ++s)
            Bf[s][nf] = *reinterpret_cast<const bf16x8*>(
                Wt + ((((h * 8 + s) * 4 + g) * 128 + c) << 3));
    }

    f32x4 acc[4][2];
    #pragma unroll
    for (int m = 0; m < 4; ++m)
        #pragma unroll
        for (int nf = 0; nf < 2; ++nf)
            acc[m][nf] = (f32x4){0.f, 0.f, 0.f, 0.f};

    #pragma unroll
    for (int s = 0; s < 8; ++s) {
        #pragma unroll
        for (int m = 0; m < 4; ++m) {
            const int r = m * 16 + li;
            const int chunk = (4 * s + g) ^ (r & 7);
            const bf16x8 af = *reinterpret_cast<const bf16x8*>(xs + r * 512 + chunk * 16);
            acc[m][0] = __builtin_amdgcn_mfma_f32_16x16x32_bf16(af, Bf[s][0], acc[m][0], 0, 0, 0);
            acc[m][1] = __builtin_amdgcn_mfma_f32_16x16x32_bf16(af, Bf[s][1], acc[m][1], 0, 0, 0);
        }
    }

    float part[4][4];
    #pragma unroll
    for (int m = 0; m < 4; ++m)
        #pragma unroll
        for (int j = 0; j < 4; ++j) part[m][j] = 0.f;

    #pragma unroll
    for (int nf = 0; nf < 2; ++nf) {
        const float a_ = av[h * QDIM + w * 32 + nf * 16 + li];
        #pragma unroll
        for (int m = 0; m < 4; ++m)
            #pragma unroll
            for (int j = 0; j < 4; ++j)
                part[m][j] = fmaf(a_, leaky(acc[m][nf][j]), part[m][j]);
    }
    #pragma unroll
    for (int mask = 1; mask < 16; mask <<= 1)
        #pragma unroll
        for (int m = 0; m < 4; ++m)
            #pragma unroll
            for (int j = 0; j < 4; ++j)
                part[m][j] += __shfl_xor(part[m][j], mask, 64);

    if (li == 0) {
        #pragma unroll
        for (int m = 0; m < 4; ++m)
            #pragma unroll
            for (int j = 0; j < 4; ++j)
                sp[w][m * 16 + g * 4 + j] = part[m][j];
    }
    __syncthreads();

    if (tid < 64) {
        const float val = (sp[0][tid] + sp[1][tid] + sp[2][tid] + sp[3][tid] + bv[h]) * TANH_PRESCALE;
        const int R = mt * 64 + tid;
        out[((R >> 10) * H_ + h) * N_ + (R & 1023)] = val;
    }
}

// ---------------------------------------------------------------------------
// K2: scores + row-norm + masked column partial-sums. One pass over e.
// grid = (64 i-chunks of 16, B), block = 512 (8 waves = half x head).
// Lane owns j = u*256 + lane*4 + c. Row PAIRS (2x ILP, r11 structure).
// Partials stored bf16. No atomics. [best measured config]
// ---------------------------------------------------------------------------
__global__ __launch_bounds__(512) void attn_kernel(
    const float* __restrict__ e,
    const float* __restrict__ qbuf, const float* __restrict__ kbuf,
    const float* __restrict__ mask, const float* __restrict__ epsp,
    ushort* __restrict__ pbuf)
{
    const int tid  = threadIdx.x;
    const int wav  = tid >> 6;
    const int h    = wav & 3;
    const int half = wav >> 2;
    const int lane = tid & 63;
    const int b    = blockIdx.y;
    const int ic   = blockIdx.x;
    const int i0   = ic * 16 + half * 8;     // even
    const float epsv = epsp[0];              // RAW: qk already carries C
    const int udiag = ic >> 4;               // (i>>8), uniform across chunk

    __shared__ f32x2 red2[4][8][64];         // 16 KB

    const f32x4* kr4 = reinterpret_cast<const f32x4*>(kbuf + (b * H_ + h) * N_);
    f32x2 kk2[8];
    #pragma unroll
    for (int u = 0; u < 4; ++u) {
        const f32x4 kv = kr4[u * 64 + lane];
        kk2[2 * u]     = __builtin_shufflevector(kv, kv, 0, 1);
        kk2[2 * u + 1] = __builtin_shufflevector(kv, kv, 2, 3);
    }

    f32x2 wacc2[8];
    #pragma unroll
    for (int p = 0; p < 8; ++p) wacc2[p] = (f32x2){0.f, 0.f};

    const float* qrow  = qbuf + (b * H_ + h) * N_;
    const float* mrow  = mask + b * N_;
    const f32x4* ebase = reinterpret_cast<const f32x4*>(e + ((size_t)b << 20)) + lane;

    const f32x2 one2 = {1.f, 1.f};
    const f32x2 m2   = {-2.f, -2.f};

    #pragma unroll
    for (int ii = 0; ii < 8; ii += 2) {
        const int iA = i0 + ii, iB = iA + 1;
        const float qiA = qrow[iA], qiB = qrow[iB];
        const f32x2 qiA2 = {qiA, qiA}, qiB2 = {qiB, qiB};
        // even/odd pair: same lane predicate, slots cc=0 (A) and cc=1 (B)
        const bool isdl = (lane == ((iA >> 2) & 63));
        const float dadd = isdl ? epsv : 0.f;

        // issue both rows' loads up front (8 independent dwordx4)
        const f32x4* erA = ebase + ((size_t)iA << 8);
        const f32x4* erB = ebase + ((size_t)iB << 8);
        f32x4 evA[4], evB[4];
        #pragma unroll
        for (int u = 0; u < 4; ++u) { evA[u] = erA[u * 64]; evB[u] = erB[u * 64]; }

        f32x2 pvA[8], pvB[8];
        f32x2 sslA = {0.f, 0.f}, sslB = {0.f, 0.f};
        #pragma unroll
        for (int u = 0; u < 4; ++u) {
            #pragma unroll
            for (int s = 0; s < 2; ++s) {
                const int p = 2 * u + s;
                const f32x2 eA2 = s ? __builtin_shufflevector(evA[u], evA[u], 2, 3)
                                    : __builtin_shufflevector(evA[u], evA[u], 0, 1);
                const f32x2 eB2 = s ? __builtin_shufflevector(evB[u], evB[u], 2, 3)
                                    : __builtin_shufflevector(evB[u], evB[u], 0, 1);
                const f32x2 qkA = qiA2 + kk2[p];
                const f32x2 qkB = qiB2 + kk2[p];
                f32x2 argA = qkA * eA2;
                f32x2 argB = qkB * eB2;
                if (u == udiag && s == ((ii & 3) >> 1)) {  // compile-time
                    argA[0] = fmaf(qkA[0], dadd, argA[0]);   // row A: cc=0
                    argB[1] = fmaf(qkB[1], dadd, argB[1]);   // row B: cc=1
                }
                f32x2 exA, exB;
                exA[0] = __builtin_amdgcn_exp2f(argA[0]);
                exB[0] = __builtin_amdgcn_exp2f(argB[0]);
                exA[1] = __builtin_amdgcn_exp2f(argA[1]);
                exB[1] = __builtin_amdgcn_exp2f(argB[1]);
                const f32x2 dA = exA + one2;
                const f32x2 dB = exB + one2;
                f32x2 rA, rB;
                rA[0] = __builtin_amdgcn_rcpf(dA[0]);
                rB[0] = __builtin_amdgcn_rcpf(dB[0]);
                rA[1] = __builtin_amdgcn_rcpf(dA[1]);
                rB[1] = __builtin_amdgcn_rcpf(dB[1]);
                const f32x2 pA = __builtin_elementwise_fma(rA, m2, one2);
                const f32x2 pB = __builtin_elementwise_fma(rB, m2, one2);
                pvA[p] = pA; pvB[p] = pB;
                sslA = __builtin_elementwise_fma(pA, pA, sslA);
                sslB = __builtin_elementwise_fma(pB, pB, sslB);
            }
        }
        // two independent reduce chains (interleavable)
        const float sA = wave_reduce_add(sslA[0] + sslA[1]);
        const float sB = wave_reduce_add(sslB[0] + sslB[1]);
        const float scaleA = mrow[iA] * __builtin_amdgcn_rcpf(sqrtf(sA) + 1e-7f);
        const float scaleB = mrow[iB] * __builtin_amdgcn_rcpf(sqrtf(sB) + 1e-7f);
        const f32x2 scA = {scaleA, scaleA}, scB = {scaleB, scaleB};
        #pragma unroll
        for (int p = 0; p < 8; ++p) {
            wacc2[p] = __builtin_elementwise_fma(scA, pvA[p], wacc2[p]);
            wacc2[p] = __builtin_elementwise_fma(scB, pvB[p], wacc2[p]);
        }
    }

    if (half == 1) {
        #pragma unroll
        for (int p = 0; p < 8; ++p) red2[h][p][lane] = wacc2[p];
    }
    __syncthreads();
    if (half == 0) {
        ushort* pr = pbuf + ((size_t)((ic * 16 + b) * H_ + h) << 10);
        #pragma unroll
        for (int u = 0; u < 4; ++u) {
            const f32x2 a = wacc2[2 * u]     + red2[h][2 * u][lane];
            const f32x2 c = wacc2[2 * u + 1] + red2[h][2 * u + 1][lane];
            ushort4 o;
            o.x = bfbits(a[0]); o.y = bfbits(a[1]);
            o.z = bfbits(c[0]); o.w = bfbits(c[1]);
            *reinterpret_cast<ushort4*>(pr + u * 256 + lane * 4) = o;
        }
    }
}

// ---------------------------------------------------------------------------
// K3a: partial-reduce (64 ic, bf16) + weighted row-sum of x (f32).
// grid 256 (b, jc of 64 j), block 256.
// ---------------------------------------------------------------------------
__global__ __launch_bounds__(256) void ypart_kernel(
    const float* __restrict__ x, const ushort* __restrict__ pbuf,
    float* __restrict__ ypart)
{
    const int tid = threadIdx.x;
    const int bx  = blockIdx.x;
    const int b   = bx >> 4;
    const int jc  = bx & 15;
    const int j0  = jc * 64;

    __shared__ float ws_[H_][64];
    {
        const int hh = tid >> 6, j = tid & 63;   // exactly 256 = 4h x 64j
        const ushort* pp = pbuf + ((size_t)(b * H_ + hh) << 10) + j0 + j;
        float s0 = 0.f, s1 = 0.f, s2 = 0.f, s3 = 0.f;
        #pragma unroll 4
        for (int ic = 0; ic < 64; ic += 4) {
            s0 += bf2f(pp[(size_t)(ic + 0) * 65536]);
            s1 += bf2f(pp[(size_t)(ic + 1) * 65536]);
            s2 += bf2f(pp[(size_t)(ic + 2) * 65536]);
            s3 += bf2f(pp[(size_t)(ic + 3) * 65536]);
        }
        ws_[hh][j] = (s0 + s1) + (s2 + s3);
    }
    __syncthreads();

    float a0 = 0.f, a1 = 0.f, a2 = 0.f, a3 = 0.f;
    const float* xcol = x + ((size_t)(b * N_ + j0)) * F_ + tid;
    #pragma unroll 4
    for (int j = 0; j < 64; ++j) {
        const float xv = xcol[(size_t)j * F_];
        a0 = fmaf(ws_[0][j], xv, a0);
        a1 = fmaf(ws_[1][j], xv, a1);
        a2 = fmaf(ws_[2][j], xv, a2);
        a3 = fmaf(ws_[3][j], xv, a3);
    }
    float* yp = ypart + (size_t)(b * 16 + jc) * (H_ * F_) + tid;
    yp[0 * F_] = a0; yp[1 * F_] = a1; yp[2 * F_] = a2; yp[3 * F_] = a3;
}

// ---------------------------------------------------------------------------
// K3b: out[b, h*128+v] = sum_f (sum_jc ypart[b,jc,h,f]) * Wv[h,f,v]
// ---------------------------------------------------------------------------
__global__ __launch_bounds__(256) void pool_kernel(
    const float* __restrict__ ypart, const float* __restrict__ Wv,
    float* __restrict__ out)
{
    const int tid = threadIdx.x;
    const int bh  = blockIdx.x;
    const int b   = bh >> 2;
    const int h   = bh & 3;
    __shared__ float ys[256];
    float s = 0.f;
    #pragma unroll
    for (int jc = 0; jc < 16; ++jc)
        s += ypart[(size_t)(b * 16 + jc) * (H_ * F_) + h * F_ + tid];
    ys[tid] = s;
    __syncthreads();
    if (tid < 128) {
        float acc = 0.f;
        const float* wv = Wv + h * (F_ * 128) + tid;
        #pragma unroll 4
        for (int f = 0; f < F_; ++f) acc = fmaf(ys[f], wv[f * 128], acc);
        out[bh * 128 + tid] = acc;
    }
}

extern "C" void kernel_launch(void* const* d_in, const int* in_sizes, int n_in,
                              void* d_out, int out_size, void* d_ws, size_t ws_size,
                              hipStream_t stream) {
    const float* e    = (const float*)d_in[0];
    const float* x    = (const float*)d_in[1];
    const float* mask = (const float*)d_in[2];
    const float* eps  = (const float*)d_in[3];
    const float* Wq   = (const float*)d_in[4];
    const float* Wk   = (const float*)d_in[5];
    const float* Wv   = (const float*)d_in[6];
    const float* aq   = (const float*)d_in[7];
    const float* bq   = (const float*)d_in[8];
    const float* ak   = (const float*)d_in[9];
    const float* bk   = (const float*)d_in[10];

    float*  qbuf  = (float*)d_ws;              // [B,H,N]         65536 f32
    float*  kbuf  = qbuf + 65536;              // [B,H,N]         65536 f32
    float*  ypartb= kbuf + 65536;              // [B,16,H,F]     262144 f32
    ushort* pbuf  = (ushort*)(ypartb + 262144);// [64,B,H,N] bf16 4194304
    ushort* Wqt   = pbuf + 4194304;            // [h][s][g][c][j] 131072
    ushort* Wkt   = Wqt + 131072;              // [h][s][g][c][j] 131072
    float*  outf  = (float*)d_out;

    convert_w<<<dim3(512, 2), 256, 0, stream>>>(Wq, Wk, Wqt, Wkt);
    qk_mfma<<<dim3(256, 4, 2), 256, 0, stream>>>(x, Wqt, Wkt, aq, bq, ak, bk, qbuf, kbuf);
    attn_kernel<<<dim3(64, 16), 512, 0, stream>>>(e, qbuf, kbuf, mask, eps, pbuf);
    ypart_kernel<<<256, 256, 0, stream>>>(x, pbuf, ypartb);
    pool_kernel<<<64, 256, 0, stream>>>(ypartb, Wv, outf);
}

// Round 18
// 73.502 us; speedup vs baseline: 1.1826x; 1.0018x over previous
//
#include <hip/hip_runtime.h>

#define B_ 16
#define N_ 1024
#define F_ 256
#define H_ 4
#define QDIM 128

// 2*log2(e): folded into q,k so tanh arg feeds v_exp_f32 (exp2) directly
#define TANH_PRESCALE 2.8853900817779268f

typedef __attribute__((ext_vector_type(8))) short bf16x8;
typedef __attribute__((ext_vector_type(4))) float f32x4;
typedef __attribute__((ext_vector_type(2))) float f32x2;

__device__ __forceinline__ float leaky(float x) {
    return x >= 0.f ? x : 0.2f * x;
}

// f32 -> bf16 bits, round-to-nearest-even
__device__ __forceinline__ unsigned short bfbits(float f) {
    unsigned u = __float_as_uint(f);
    return (unsigned short)((u + 0x7fffu + ((u >> 16) & 1u)) >> 16);
}

__device__ __forceinline__ float bf2f(unsigned short u) {
    return __uint_as_float(((unsigned)u) << 16);
}

// DPP cross-lane add level (full-rate VALU, no LDS pipe). ctrl immediate.
template <int CTRL>
__device__ __forceinline__ float dpp_add(float x) {
    return x + __int_as_float(
        __builtin_amdgcn_update_dpp(0, __float_as_int(x), CTRL, 0xf, 0xf, true));
}

// wave64 sum reduce: 4 DPP levels + 2 shuffle levels.
__device__ __forceinline__ float wave_reduce_add(float x) {
    x = dpp_add<0xB1>(x);     // quad_perm xor1
    x = dpp_add<0x4E>(x);     // quad_perm xor2
    x = dpp_add<0x141>(x);    // row_half_mirror (== xor4 here)
    x = dpp_add<0x140>(x);    // row_mirror (== xor8 here)
    x += __shfl_xor(x, 16, 64);
    x += __shfl_xor(x, 32, 64);
    return x;
}

// ---------------------------------------------------------------------------
// K0: Wq/Wk [h][f][q] f32 -> fragment-ordered bf16: W2[h][s][g][c][j],
// f = s*32 + 8g + j, q = c. Makes qk_mfma's B-frag loads COALESCED
// (16 lanes x 16B contiguous per group). 1 MB, tiny.
// ---------------------------------------------------------------------------
__global__ __launch_bounds__(256) void convert_w(
    const float* __restrict__ Wq, const float* __restrict__ Wk,
    ushort* __restrict__ Wqt, ushort* __restrict__ Wkt)
{
    const int t = blockIdx.x * 256 + threadIdx.x;     // 0..131071
    const int j = t & 7;
    const int c = (t >> 3) & 127;
    const int g = (t >> 10) & 3;
    const int s = (t >> 12) & 7;
    const int h = t >> 15;
    const int f = s * 32 + 8 * g + j;
    const float* W = blockIdx.y ? Wk : Wq;
    ushort* O = blockIdx.y ? Wkt : Wqt;
    O[t] = bfbits(W[(h * 256 + f) * 128 + c]);
}

// ---------------------------------------------------------------------------
// K1: MFMA q/k projection. grid (256 m-tiles, 4 heads, 2 {q,k}), block 256.
// Stages A directly from f32 x with in-register RNE cvt; B-frags from the
// fragment-ordered W2 layout (coalesced). [proven r16 config]
// ---------------------------------------------------------------------------
__global__ __launch_bounds__(256) void qk_mfma(
    const float* __restrict__ x,
    const ushort* __restrict__ Wqt, const ushort* __restrict__ Wkt,
    const float* __restrict__ aq, const float* __restrict__ bq,
    const float* __restrict__ ak, const float* __restrict__ bk,
    float* __restrict__ qbuf, float* __restrict__ kbuf)
{
    const int tid = threadIdx.x;
    const int mt  = blockIdx.x;
    const int h   = blockIdx.y;
    const bool isQ = (blockIdx.z == 0);
    const ushort* Wt = isQ ? Wqt : Wkt;
    const float*  av = isQ ? aq : ak;
    const float*  bv = isQ ? bq : bk;
    float* out = isQ ? qbuf : kbuf;

    __shared__ char  xs[64 * 512];       // 64 rows x 256 bf16 (swizzled)
    __shared__ float sp[4][64];

    // stage A from f32: thread t -> row r = t>>2, bf16 16B chunks c=(t&3)+4i
    {
        const int r = tid >> 2;
        const float* src = x + (size_t)(mt * 64 + r) * 256;
        #pragma unroll
        for (int i = 0; i < 8; ++i) {
            const int c = (tid & 3) + 4 * i;
            const float4 v0 = *reinterpret_cast<const float4*>(src + c * 8);
            const float4 v1 = *reinterpret_cast<const float4*>(src + c * 8 + 4);
            ushort4 o0, o1;
            o0.x = bfbits(v0.x); o0.y = bfbits(v0.y); o0.z = bfbits(v0.z); o0.w = bfbits(v0.w);
            o1.x = bfbits(v1.x); o1.y = bfbits(v1.y); o1.z = bfbits(v1.z); o1.w = bfbits(v1.w);
            char* dst = xs + r * 512 + ((c ^ (r & 7)) << 4);
            *reinterpret_cast<ushort4*>(dst) = o0;
            *reinterpret_cast<ushort4*>(dst + 8) = o1;
        }
    }
    __syncthreads();

    const int l  = tid & 63, w = tid >> 6;
    const int g  = l >> 4, li = l & 15;

    // B frags: Bf[s][nf][j] = W[h][s*32+8g+j][c], c = w*32+nf*16+li.
    // W2 addr = (((h*8+s)*4+g)*128 + c)*8 -> lanes li consecutive 16B chunks.
    bf16x8 Bf[8][2];
    #pragma unroll
    for (int nf = 0; nf < 2; ++nf) {
        const int c = w * 32 + nf * 16 + li;
        #pragma unroll
        for (int s = 0; s < 8; ++s)
            Bf[s][nf] = *reinterpret_cast<const bf16x8*>(
                Wt + ((((h * 8 + s) * 4 + g) * 128 + c) << 3));
    }

    f32x4 acc[4][2];
    #pragma unroll
    for (int m = 0; m < 4; ++m)
        #pragma unroll
        for (int nf = 0; nf < 2; ++nf)
            acc[m][nf] = (f32x4){0.f, 0.f, 0.f, 0.f};

    #pragma unroll
    for (int s = 0; s < 8; ++s) {
        #pragma unroll
        for (int m = 0; m < 4; ++m) {
            const int r = m * 16 + li;
            const int chunk = (4 * s + g) ^ (r & 7);
            const bf16x8 af = *reinterpret_cast<const bf16x8*>(xs + r * 512 + chunk * 16);
            acc[m][0] = __builtin_amdgcn_mfma_f32_16x16x32_bf16(af, Bf[s][0], acc[m][0], 0, 0, 0);
            acc[m][1] = __builtin_amdgcn_mfma_f32_16x16x32_bf16(af, Bf[s][1], acc[m][1], 0, 0, 0);
        }
    }

    float part[4][4];
    #pragma unroll
    for (int m = 0; m < 4; ++m)
        #pragma unroll
        for (int j = 0; j < 4; ++j) part[m][j] = 0.f;

    #pragma unroll
    for (int nf = 0; nf < 2; ++nf) {
        const float a_ = av[h * QDIM + w * 32 + nf * 16 + li];
        #pragma unroll
        for (int m = 0; m < 4; ++m)
            #pragma unroll
            for (int j = 0; j < 4; ++j)
                part[m][j] = fmaf(a_, leaky(acc[m][nf][j]), part[m][j]);
    }
    #pragma unroll
    for (int mask = 1; mask < 16; mask <<= 1)
        #pragma unroll
        for (int m = 0; m < 4; ++m)
            #pragma unroll
            for (int j = 0; j < 4; ++j)
                part[m][j] += __shfl_xor(part[m][j], mask, 64);

    if (li == 0) {
        #pragma unroll
        for (int m = 0; m < 4; ++m)
            #pragma unroll
            for (int j = 0; j < 4; ++j)
                sp[w][m * 16 + g * 4 + j] = part[m][j];
    }
    __syncthreads();

    if (tid < 64) {
        const float val = (sp[0][tid] + sp[1][tid] + sp[2][tid] + sp[3][tid] + bv[h]) * TANH_PRESCALE;
        const int R = mt * 64 + tid;
        out[((R >> 10) * H_ + h) * N_ + (R & 1023)] = val;
    }
}

// ---------------------------------------------------------------------------
// K2: scores + row-norm + masked column partial-sums. One pass over e.
// grid = (64 i-chunks of 16, B), block = 512 (8 waves = half x head).
// Lane owns j = u*256 + lane*4 + c. Row PAIRS (2x ILP, r11 structure).
// Partials stored bf16. No atomics. [best measured config]
// ---------------------------------------------------------------------------
__global__ __launch_bounds__(512) void attn_kernel(
    const float* __restrict__ e,
    const float* __restrict__ qbuf, const float* __restrict__ kbuf,
    const float* __restrict__ mask, const float* __restrict__ epsp,
    ushort* __restrict__ pbuf)
{
    const int tid  = threadIdx.x;
    const int wav  = tid >> 6;
    const int h    = wav & 3;
    const int half = wav >> 2;
    const int lane = tid & 63;
    const int b    = blockIdx.y;
    const int ic   = blockIdx.x;
    const int i0   = ic * 16 + half * 8;     // even
    const float epsv = epsp[0];              // RAW: qk already carries C
    const int udiag = ic >> 4;               // (i>>8), uniform across chunk

    __shared__ f32x2 red2[4][8][64];         // 16 KB

    const f32x4* kr4 = reinterpret_cast<const f32x4*>(kbuf + (b * H_ + h) * N_);
    f32x2 kk2[8];
    #pragma unroll
    for (int u = 0; u < 4; ++u) {
        const f32x4 kv = kr4[u * 64 + lane];
        kk2[2 * u]     = __builtin_shufflevector(kv, kv, 0, 1);
        kk2[2 * u + 1] = __builtin_shufflevector(kv, kv, 2, 3);
    }

    f32x2 wacc2[8];
    #pragma unroll
    for (int p = 0; p < 8; ++p) wacc2[p] = (f32x2){0.f, 0.f};

    const float* qrow  = qbuf + (b * H_ + h) * N_;
    const float* mrow  = mask + b * N_;
    const f32x4* ebase = reinterpret_cast<const f32x4*>(e + ((size_t)b << 20)) + lane;

    const f32x2 one2 = {1.f, 1.f};
    const f32x2 m2   = {-2.f, -2.f};

    #pragma unroll
    for (int ii = 0; ii < 8; ii += 2) {
        const int iA = i0 + ii, iB = iA + 1;
        const float qiA = qrow[iA], qiB = qrow[iB];
        const f32x2 qiA2 = {qiA, qiA}, qiB2 = {qiB, qiB};
        // even/odd pair: same lane predicate, slots cc=0 (A) and cc=1 (B)
        const bool isdl = (lane == ((iA >> 2) & 63));
        const float dadd = isdl ? epsv : 0.f;

        // issue both rows' loads up front (8 independent dwordx4)
        const f32x4* erA = ebase + ((size_t)iA << 8);
        const f32x4* erB = ebase + ((size_t)iB << 8);
        f32x4 evA[4], evB[4];
        #pragma unroll
        for (int u = 0; u < 4; ++u) { evA[u] = erA[u * 64]; evB[u] = erB[u * 64]; }

        f32x2 pvA[8], pvB[8];
        f32x2 sslA = {0.f, 0.f}, sslB = {0.f, 0.f};
        #pragma unroll
        for (int u = 0; u < 4; ++u) {
            #pragma unroll
            for (int s = 0; s < 2; ++s) {
                const int p = 2 * u + s;
                const f32x2 eA2 = s ? __builtin_shufflevector(evA[u], evA[u], 2, 3)
                                    : __builtin_shufflevector(evA[u], evA[u], 0, 1);
                const f32x2 eB2 = s ? __builtin_shufflevector(evB[u], evB[u], 2, 3)
                                    : __builtin_shufflevector(evB[u], evB[u], 0, 1);
                const f32x2 qkA = qiA2 + kk2[p];
                const f32x2 qkB = qiB2 + kk2[p];
                f32x2 argA = qkA * eA2;
                f32x2 argB = qkB * eB2;
                if (u == udiag && s == ((ii & 3) >> 1)) {  // compile-time
                    argA[0] = fmaf(qkA[0], dadd, argA[0]);   // row A: cc=0
                    argB[1] = fmaf(qkB[1], dadd, argB[1]);   // row B: cc=1
                }
                f32x2 exA, exB;
                exA[0] = __builtin_amdgcn_exp2f(argA[0]);
                exB[0] = __builtin_amdgcn_exp2f(argB[0]);
                exA[1] = __builtin_amdgcn_exp2f(argA[1]);
                exB[1] = __builtin_amdgcn_exp2f(argB[1]);
                const f32x2 dA = exA + one2;
                const f32x2 dB = exB + one2;
                f32x2 rA, rB;
                rA[0] = __builtin_amdgcn_rcpf(dA[0]);
                rB[0] = __builtin_amdgcn_rcpf(dB[0]);
                rA[1] = __builtin_amdgcn_rcpf(dA[1]);
                rB[1] = __builtin_amdgcn_rcpf(dB[1]);
                const f32x2 pA = __builtin_elementwise_fma(rA, m2, one2);
                const f32x2 pB = __builtin_elementwise_fma(rB, m2, one2);
                pvA[p] = pA; pvB[p] = pB;
                sslA = __builtin_elementwise_fma(pA, pA, sslA);
                sslB = __builtin_elementwise_fma(pB, pB, sslB);
            }
        }
        // two independent reduce chains (interleavable)
        const float sA = wave_reduce_add(sslA[0] + sslA[1]);
        const float sB = wave_reduce_add(sslB[0] + sslB[1]);
        const float scaleA = mrow[iA] * __builtin_amdgcn_rcpf(sqrtf(sA) + 1e-7f);
        const float scaleB = mrow[iB] * __builtin_amdgcn_rcpf(sqrtf(sB) + 1e-7f);
        const f32x2 scA = {scaleA, scaleA}, scB = {scaleB, scaleB};
        #pragma unroll
        for (int p = 0; p < 8; ++p) {
            wacc2[p] = __builtin_elementwise_fma(scA, pvA[p], wacc2[p]);
            wacc2[p] = __builtin_elementwise_fma(scB, pvB[p], wacc2[p]);
        }
    }

    if (half == 1) {
        #pragma unroll
        for (int p = 0; p < 8; ++p) red2[h][p][lane] = wacc2[p];
    }
    __syncthreads();
    if (half == 0) {
        ushort* pr = pbuf + ((size_t)((ic * 16 + b) * H_ + h) << 10);
        #pragma unroll
        for (int u = 0; u < 4; ++u) {
            const f32x2 a = wacc2[2 * u]     + red2[h][2 * u][lane];
            const f32x2 c = wacc2[2 * u + 1] + red2[h][2 * u + 1][lane];
            ushort4 o;
            o.x = bfbits(a[0]); o.y = bfbits(a[1]);
            o.z = bfbits(c[0]); o.w = bfbits(c[1]);
            *reinterpret_cast<ushort4*>(pr + u * 256 + lane * 4) = o;
        }
    }
}

// ---------------------------------------------------------------------------
// K3a: partial-reduce (64 ic, bf16) + weighted row-sum of x (f32).
// grid 256 (b, jc of 64 j), block 256.
// ---------------------------------------------------------------------------
__global__ __launch_bounds__(256) void ypart_kernel(
    const float* __restrict__ x, const ushort* __restrict__ pbuf,
    float* __restrict__ ypart)
{
    const int tid = threadIdx.x;
    const int bx  = blockIdx.x;
    const int b   = bx >> 4;
    const int jc  = bx & 15;
    const int j0  = jc * 64;

    __shared__ float ws_[H_][64];
    {
        const int hh = tid >> 6, j = tid & 63;   // exactly 256 = 4h x 64j
        const ushort* pp = pbuf + ((size_t)(b * H_ + hh) << 10) + j0 + j;
        float s0 = 0.f, s1 = 0.f, s2 = 0.f, s3 = 0.f;
        #pragma unroll 4
        for (int ic = 0; ic < 64; ic += 4) {
            s0 += bf2f(pp[(size_t)(ic + 0) * 65536]);
            s1 += bf2f(pp[(size_t)(ic + 1) * 65536]);
            s2 += bf2f(pp[(size_t)(ic + 2) * 65536]);
            s3 += bf2f(pp[(size_t)(ic + 3) * 65536]);
        }
        ws_[hh][j] = (s0 + s1) + (s2 + s3);
    }
    __syncthreads();

    float a0 = 0.f, a1 = 0.f, a2 = 0.f, a3 = 0.f;
    const float* xcol = x + ((size_t)(b * N_ + j0)) * F_ + tid;
    #pragma unroll 4
    for (int j = 0; j < 64; ++j) {
        const float xv = xcol[(size_t)j * F_];
        a0 = fmaf(ws_[0][j], xv, a0);
        a1 = fmaf(ws_[1][j], xv, a1);
        a2 = fmaf(ws_[2][j], xv, a2);
        a3 = fmaf(ws_[3][j], xv, a3);
    }
    float* yp = ypart + (size_t)(b * 16 + jc) * (H_ * F_) + tid;
    yp[0 * F_] = a0; yp[1 * F_] = a1; yp[2 * F_] = a2; yp[3 * F_] = a3;
}

// ---------------------------------------------------------------------------
// K3b: out[b, h*128+v] = sum_f (sum_jc ypart[b,jc,h,f]) * Wv[h,f,v]
// ---------------------------------------------------------------------------
__global__ __launch_bounds__(256) void pool_kernel(
    const float* __restrict__ ypart, const float* __restrict__ Wv,
    float* __restrict__ out)
{
    const int tid = threadIdx.x;
    const int bh  = blockIdx.x;
    const int b   = bh >> 2;
    const int h   = bh & 3;
    __shared__ float ys[256];
    float s = 0.f;
    #pragma unroll
    for (int jc = 0; jc < 16; ++jc)
        s += ypart[(size_t)(b * 16 + jc) * (H_ * F_) + h * F_ + tid];
    ys[tid] = s;
    __syncthreads();
    if (tid < 128) {
        float acc = 0.f;
        const float* wv = Wv + h * (F_ * 128) + tid;
        #pragma unroll 4
        for (int f = 0; f < F_; ++f) acc = fmaf(ys[f], wv[f * 128], acc);
        out[bh * 128 + tid] = acc;
    }
}

extern "C" void kernel_launch(void* const* d_in, const int* in_sizes, int n_in,
                              void* d_out, int out_size, void* d_ws, size_t ws_size,
                              hipStream_t stream) {
    const float* e    = (const float*)d_in[0];
    const float* x    = (const float*)d_in[1];
    const float* mask = (const float*)d_in[2];
    const float* eps  = (const float*)d_in[3];
    const float* Wq   = (const float*)d_in[4];
    const float* Wk   = (const float*)d_in[5];
    const float* Wv   = (const float*)d_in[6];
    const float* aq   = (const float*)d_in[7];
    const float* bq   = (const float*)d_in[8];
    const float* ak   = (const float*)d_in[9];
    const float* bk   = (const float*)d_in[10];

    float*  qbuf  = (float*)d_ws;              // [B,H,N]         65536 f32
    float*  kbuf  = qbuf + 65536;              // [B,H,N]         65536 f32
    float*  ypartb= kbuf + 65536;              // [B,16,H,F]     262144 f32
    ushort* pbuf  = (ushort*)(ypartb + 262144);// [64,B,H,N] bf16 4194304
    ushort* Wqt   = pbuf + 4194304;            // [h][s][g][c][j] 131072
    ushort* Wkt   = Wqt + 131072;              // [h][s][g][c][j] 131072
    float*  outf  = (float*)d_out;

    convert_w<<<dim3(512, 2), 256, 0, stream>>>(Wq, Wk, Wqt, Wkt);
    qk_mfma<<<dim3(256, 4, 2), 256, 0, stream>>>(x, Wqt, Wkt, aq, bq, ak, bk, qbuf, kbuf);
    attn_kernel<<<dim3(64, 16), 512, 0, stream>>>(e, qbuf, kbuf, mask, eps, pbuf);
    ypart_kernel<<<256, 256, 0, stream>>>(x, pbuf, ypartb);
    pool_kernel<<<64, 256, 0, stream>>>(ypartb, Wv, outf);
}